// Round 12
// baseline (151.105 us; speedup 1.0000x reference)
//
#include <hip/hip_runtime.h>
#include <stdint.h>

#define N_BOXES 6000
#define NT 94            // tiles of 64 rows
#define NROWS 6144       // padded rows (1024 threads x 6)
#define ECAP 16384       // edge buffer capacity (expected ~5-10k edges)
#define IOU_THR 0.5f
#define CONF_THR 0.6f

typedef unsigned long long u64;
typedef unsigned int u32;
typedef unsigned short u16;

__device__ __forceinline__ u64 rdlane64(u64 v, int l) {
    unsigned lo = (unsigned)__builtin_amdgcn_readlane((int)(unsigned)v, l);
    unsigned hi = (unsigned)__builtin_amdgcn_readlane((int)(unsigned)(v >> 32), l);
    return ((u64)hi << 32) | lo;
}

// ---- kernel 1: fused sort (keys + rank + scatter) -------------------------
// scores uniform [0,1) -> raw float bits monotone. key = (~bits<<32)|index:
// ascending u64 == descending score, ties by ascending index (JAX stable argsort).
// LDS-staged keys, broadcast ds_read compares.
__global__ void __launch_bounds__(1024) k_sort(const float* __restrict__ scores,
                                               const float4* __restrict__ boxes,
                                               int* __restrict__ sidx,
                                               float4* __restrict__ sboxes,
                                               int* __restrict__ ecnt) {
    __shared__ u64 kt[N_BOXES];      // 48,000 B
    __shared__ int part[1024];
    const int tid = threadIdx.x;
    if (blockIdx.x == 0 && tid == 0) *ecnt = 0;

    for (int j = tid; j < N_BOXES; j += 1024) {
        unsigned inv = ~__float_as_uint(scores[j]);
        kt[j] = ((u64)inv << 32) | (unsigned)j;
    }
    __syncthreads();
    const int il = tid & 63;
    const int i = blockIdx.x * 64 + il;
    const int j0 = (tid >> 6) * 375;         // 16 segments of 375 (wave-uniform)
    u64 mykey = (i < N_BOXES) ? kt[i] : 0ull;
    int cntr = 0;
#pragma unroll 5
    for (int jj = 0; jj < 375; ++jj)
        cntr += (kt[j0 + jj] < mykey) ? 1 : 0;
    part[tid] = cntr;
    __syncthreads();
    if (tid < 64 && i < N_BOXES) {
        int r = 0;
#pragma unroll
        for (int s = 0; s < 16; ++s) r += part[il + 64 * s];
        sidx[r] = i;                 // keys distinct -> permutation
        sboxes[r] = boxes[i];
    }
}

// ---- kernel 2: pairwise IoU -> compact edge list --------------------------
// grid (24, 94), 256 threads: block covers cols [bx*256, bx*256+256) vs rows
// [by*64, by*64+64). Every (row, col>row) pair with iou>0.5 appends one edge
// (row<<16)|col. In-tile edges included (k_scan's resolve rebuilds diag words
// from them).
__global__ void __launch_bounds__(256) k_mask(const float4* __restrict__ sboxes,
                                              u32* __restrict__ edges,
                                              int* __restrict__ ecnt) {
    const int rt = blockIdx.y;
    const int row0 = rt * 64;
    if (blockIdx.x * 256 + 255 < row0) return;   // whole block below diagonal
    const int tid = threadIdx.x;
    __shared__ float4 rb[64];
    const int rows = min(64, N_BOXES - row0);
    if (tid < rows) rb[tid] = sboxes[row0 + tid];
    __syncthreads();
    const int j = blockIdx.x * 256 + tid;
    const bool jvalid = (j < N_BOXES);
    float4 cb = make_float4(0.f, 0.f, 1.f, 1.f);
    if (jvalid) cb = sboxes[j];
    const float carea = (cb.z - cb.x) * (cb.w - cb.y);
    for (int i = 0; i < rows; ++i) {
        float4 rbx = rb[i];
        float rarea = (rbx.z - rbx.x) * (rbx.w - rbx.y);
        // identical f32 op order as the reference (_pairwise_iou)
        float iw = fmaxf(fminf(rbx.z, cb.z) - fmaxf(rbx.x, cb.x), 0.f);
        float ih = fmaxf(fminf(rbx.w, cb.w) - fmaxf(rbx.y, cb.y), 0.f);
        float inter = iw * ih;
        float iou = inter / ((rarea + carea) - inter);
        int row = row0 + i;
        if (jvalid && (j > row) && (iou > IOU_THR)) {
            int e = atomicAdd(ecnt, 1);
            if (e < ECAP) edges[e] = ((u32)row << 16) | (u32)j;  // guarded
        }
    }
}

// ---- kernel 3: greedy scan — CSR in LDS, serial loop all-LDS --------------
// Phases (1024 threads): zero -> count rows -> in-place prefix scan (shuffle)
// -> scatter to CSR with advancing cursors -> wave 0 alone runs the 94-tile
// greedy scan with ZERO global loads in the loop (single-wave DS ops are
// in-order, so removed[t] reads see all earlier scatters without barriers).
__global__ void __launch_bounds__(1024) k_scan(const u32* __restrict__ edges,
                                               const int* __restrict__ ecnt,
                                               u64* __restrict__ keep) {
    __shared__ u32 rowptr[NROWS];    // counts -> starts -> cursors-> ends (24,576 B)
    __shared__ u16 csr[ECAP];        // col entries                   (32,768 B)
    __shared__ u64 removed[NT];      //                               (    752 B)
    __shared__ u32 aux[16];
    const int tid  = threadIdx.x;
    const int lane = tid & 63;
    const int wv   = tid >> 6;

    // zero
    {
        int b = tid * 6;
#pragma unroll
        for (int k = 0; k < 6; ++k) rowptr[b + k] = 0;
        if (tid < NT) removed[tid] = 0;
    }
    __syncthreads();

    int ne = *ecnt;                  // broadcast load
    if (ne > ECAP) ne = ECAP;

    // pass 1: count edges per row
    for (int i = tid; i < ne; i += 1024)
        atomicAdd(&rowptr[edges[i] >> 16], 1u);
    __syncthreads();

    // in-place exclusive prefix scan (thread = 6 rows; wave shuffle scan; aux)
    {
        int b = tid * 6;
        u32 c0 = rowptr[b], c1 = rowptr[b + 1], c2 = rowptr[b + 2],
            c3 = rowptr[b + 3], c4 = rowptr[b + 4], c5 = rowptr[b + 5];
        u32 s = c0 + c1 + c2 + c3 + c4 + c5;
        u32 inc = s;
        for (int off = 1; off < 64; off <<= 1) {
            u32 v = __shfl_up(inc, off);
            if (lane >= off) inc += v;
        }
        if (lane == 63) aux[wv] = inc;
        __syncthreads();
        u32 woff = 0;
        for (int w = 0; w < wv; ++w) woff += aux[w];
        u32 run = woff + inc - s;    // exclusive start of this thread's rows
        rowptr[b] = run; run += c0;
        rowptr[b + 1] = run; run += c1;
        rowptr[b + 2] = run; run += c2;
        rowptr[b + 3] = run; run += c3;
        rowptr[b + 4] = run; run += c4;
        rowptr[b + 5] = run;
    }
    __syncthreads();

    // pass 2: scatter cols; cursors advance so rowptr[r] becomes END of row r
    for (int i = tid; i < ne; i += 1024) {
        u32 e = edges[i];
        u32 slot = atomicAdd(&rowptr[e >> 16], 1u);
        csr[slot] = (u16)(e & 0xFFFFu);
    }
    __syncthreads();

    // phase C: single wave, in-order DS, zero barriers
    if (wv == 0) {
        for (int t = 0; t < NT; ++t) {
            const int r = t * 64 + lane;
            const u32 end = rowptr[r];
            const u32 beg = (r == 0) ? 0u : rowptr[r - 1];
            const int lim = (t + 1) * 64;
            u64 d = 0;                       // in-tile suppression word
            for (u32 k = beg; k < end; ++k) {
                int col = csr[k];
                if (col < lim) d |= 1ull << (col & 63);
            }
            const u64 nz = __ballot(d != 0ull);
            const int rem = N_BOXES - t * 64;
            const u64 valid = (rem >= 64) ? ~0ull : ((1ull << rem) - 1ull);
            u64 c = valid & ~removed[t];     // sees all earlier scatters
            u64 kw = 0;
            while (c) {
                u64 blockers = c & nz;
                if (!blockers) { kw |= c; break; }   // bulk-keep rest
                int g = (int)__builtin_ctzll(blockers);
                u64 below = c & ((1ull << g) - 1ull);
                kw |= below | (1ull << g);
                u64 df = rdlane64(d, g);             // bits > g only
                c &= ~(df | below | (1ull << g));
            }
            if (lane == 0) keep[t] = kw;     // fire-and-forget
            if ((kw >> lane) & 1ull) {       // scatter kept rows' edges
                for (u32 k = beg; k < end; ++k) {
                    int col = csr[k];        // in-tile cols land in removed[t]
                    atomicOr(&removed[col >> 6], 1ull << (col & 63));  // (post-read: harmless)
                }
            }
        }
    }
}

// ---- kernel 4: epilogue — parallel, 24 blocks -----------------------------
__global__ void __launch_bounds__(256) k_out(const int* __restrict__ sidx,
                                             const float* __restrict__ scores,
                                             const u64* __restrict__ keep,
                                             float* __restrict__ out) {
    int p = blockIdx.x * 256 + threadIdx.x;
    if (p < N_BOXES) {
        int orig = sidx[p];
        float s = scores[orig];
        bool k = (keep[p >> 6] >> (p & 63)) & 1ull;
        out[orig] = (k && (s >= CONF_THR)) ? s : 0.0f;  // writes ALL outputs
    }
}

extern "C" void kernel_launch(void* const* d_in, const int* in_sizes, int n_in,
                              void* d_out, int out_size, void* d_ws, size_t ws_size,
                              hipStream_t stream) {
    const float* boxes  = (const float*)d_in[0];    // [6000,4]
    const float* scores = (const float*)d_in[1];    // [6000]
    float* out = (float*)d_out;                     // [6000]

    // workspace layout
    char* ws = (char*)d_ws;
    u32*    edges  = (u32*)(ws);                    // 16384*4 = 65,536 B
    int*    ecnt   = (int*)(ws + 65536);            // 4 B (pad to 16)
    int*    sidx   = (int*)(ws + 65552);            // 24,000 B
    float4* sboxes = (float4*)(ws + 89552);         // 96,000 B (16B aligned)
    u64*    keep   = (u64*)(ws + 185552);           // 94*8 = 752 B

    k_sort<<<dim3(NT), dim3(1024), 0, stream>>>(scores, (const float4*)boxes,
                                                sidx, sboxes, ecnt);
    k_mask<<<dim3(24, NT), dim3(256), 0, stream>>>((const float4*)sboxes, edges, ecnt);
    k_scan<<<dim3(1), dim3(1024), 0, stream>>>(edges, ecnt, keep);
    k_out <<<dim3(24), dim3(256), 0, stream>>>(sidx, scores, keep, out);
}

// Round 15
// 141.202 us; speedup vs baseline: 1.0701x; 1.0701x over previous
//
#include <hip/hip_runtime.h>
#include <stdint.h>

#define N_BOXES 6000
#define NT 94              // tiles of 64 sorted rows
#define NROWS 6016         // padded rows for diagw
#define ECAP 24576         // cross-tile edge cap (R12 passed with 16384 incl. in-tile)
#define IOU_THR 0.5f
#define CONF_THR 0.6f

typedef unsigned long long u64;
typedef unsigned int u32;
typedef unsigned short u16;
typedef unsigned char u8;

__device__ __forceinline__ u64 rdlane64(u64 v, int l) {
    unsigned lo = (unsigned)__builtin_amdgcn_readlane((int)(unsigned)v, l);
    unsigned hi = (unsigned)__builtin_amdgcn_readlane((int)(unsigned)(v >> 32), l);
    return ((u64)hi << 32) | lo;
}

// ---- kernel 1: fused sort (keys + rank + scatter) — Round-10-proven -------
// scores uniform [0,1) -> raw float bits monotone. key = (~bits<<32)|index:
// ascending u64 == descending score, ties by ascending index (JAX stable argsort).
__global__ void __launch_bounds__(1024) k_sort(const float* __restrict__ scores,
                                               const float4* __restrict__ boxes,
                                               int* __restrict__ sidx,
                                               float4* __restrict__ sboxes,
                                               int* __restrict__ ecnt) {
    __shared__ u64 kt[N_BOXES];      // 48,000 B
    __shared__ int part[1024];
    const int tid = threadIdx.x;
    if (blockIdx.x == 0 && tid == 0) *ecnt = 0;
    for (int j = tid; j < N_BOXES; j += 1024) {
        unsigned inv = ~__float_as_uint(scores[j]);
        kt[j] = ((u64)inv << 32) | (unsigned)j;
    }
    __syncthreads();
    const int il = tid & 63;
    const int i = blockIdx.x * 64 + il;
    const int j0 = (tid >> 6) * 375;         // 16 segments of 375 (wave-uniform)
    u64 mykey = (i < N_BOXES) ? kt[i] : 0ull;
    int cntr = 0;
#pragma unroll 5
    for (int jj = 0; jj < 375; ++jj)
        cntr += (kt[j0 + jj] < mykey) ? 1 : 0;
    part[tid] = cntr;
    __syncthreads();
    if (tid < 64 && i < N_BOXES) {
        int r = 0;
#pragma unroll
        for (int s = 0; s < 16; ++s) r += part[il + 64 * s];
        sidx[r] = i;                 // keys distinct -> permutation
        sboxes[r] = boxes[i];
    }
}

// ---- kernel 2: pairwise IoU -> diagw (in-tile) + flat cross edges ---------
// Round-10-proven structure: block = 1 wave, grid (ct, rt) upper-triangular.
// Diagonal blocks ballot in-tile suppressions into diagw[row] (proven R10/11);
// off-diagonal predicates append (row<<16|col) to the flat list (proven R12).
__global__ void k_mask(const float4* __restrict__ sboxes,
                       u32* __restrict__ edges, int* __restrict__ ecnt,
                       u64* __restrict__ diagw) {
    int ct = blockIdx.x, rt = blockIdx.y;
    if (ct < rt) return;
    int lane = threadIdx.x;
    __shared__ float4 rb[64];
    int row0 = rt * 64;
    int rows = min(64, N_BOXES - row0);
    if (lane < rows) rb[lane] = sboxes[row0 + lane];
    __syncthreads();
    int j = ct * 64 + lane;
    bool jvalid = (j < N_BOXES);
    float4 cb = make_float4(0.f, 0.f, 1.f, 1.f);
    if (jvalid) cb = sboxes[j];
    float carea = (cb.z - cb.x) * (cb.w - cb.y);
    bool isdiag = (ct == rt);
    for (int i = 0; i < rows; ++i) {
        float4 rbx = rb[i];
        float rarea = (rbx.z - rbx.x) * (rbx.w - rbx.y);
        // identical f32 op order as the reference (_pairwise_iou)
        float iw = fmaxf(fminf(rbx.z, cb.z) - fmaxf(rbx.x, cb.x), 0.f);
        float ih = fmaxf(fminf(rbx.w, cb.w) - fmaxf(rbx.y, cb.y), 0.f);
        float inter = iw * ih;
        float iou = inter / ((rarea + carea) - inter);
        int row = row0 + i;
        bool pred = jvalid && (j > row) && (iou > IOU_THR);
        if (isdiag) {
            u64 bal = __ballot(pred);
            if (lane == (i & 63)) diagw[row] = bal;
        } else if (pred) {
            int e = atomicAdd(ecnt, 1);
            if (e < ECAP) edges[e] = ((u32)row << 16) | (u32)j;
        }
    }
}

// ---- kernel 3: greedy scan (all-LDS: diag + tile-grouped CSR) + epilogue --
// Build (1024 thr): stage diagw -> LDS; count cross edges per tile -> prefix
// scan -> scatter into tile-grouped u16/u8 CSR.
// Serial (wave 0): d = one ds_read_b64 from staged diag (no rebuild — the
// R13/R14 dscratch mechanism is gone); proven bulk-keep resolve; simple
// edge-parallel scatter (lane = edge) into removed[]. Single-wave DS is
// in-order, zero barriers in the loop.
// Epilogue (1024 thr): masked scores through the sort permutation.
__global__ void __launch_bounds__(1024) k_scan(const u32* __restrict__ edges,
                                               const int* __restrict__ ecnt,
                                               const u64* __restrict__ diagw,
                                               const int* __restrict__ sidx,
                                               const float* __restrict__ scores,
                                               float* __restrict__ out) {
    __shared__ u64 ldiag[NROWS];         // 48,128 B
    __shared__ u16 ccol[ECAP];           // 49,152 B
    __shared__ u8  crl[ECAP];            // 24,576 B
    __shared__ u32 tilestart[96], cursor[96], scanbuf[96];
    __shared__ u64 removed[96];
    __shared__ u64 kwbuf[96];
    const int tid = threadIdx.x;

    if (tid < 96) { cursor[tid] = 0; removed[tid] = 0; }
    for (int k = tid; k < NROWS; k += 1024) ldiag[k] = diagw[k];
    __syncthreads();
    const int ne = min(*ecnt, ECAP);
    for (int k = tid; k < ne; k += 1024)
        atomicAdd(&cursor[(edges[k] >> 16) >> 6], 1u);
    __syncthreads();
    // exclusive prefix scan over 96 tile counts (Hillis-Steele)
    u32 myc = (tid < 96) ? cursor[tid] : 0;
    if (tid < 96) scanbuf[tid] = myc;
    __syncthreads();
    for (int off = 1; off < 96; off <<= 1) {
        u32 v = 0;
        if (tid < 96 && tid >= off) v = scanbuf[tid - off];
        __syncthreads();
        if (tid < 96) scanbuf[tid] += v;
        __syncthreads();
    }
    if (tid < 96) {
        u32 st = scanbuf[tid] - myc;
        tilestart[tid] = st;
        cursor[tid] = st;
    }
    __syncthreads();
    // scatter cross edges into tile-grouped CSR (cursor ends at tile end)
    for (int k = tid; k < ne; k += 1024) {
        u32 e = edges[k];
        u32 row = e >> 16, col = e & 0xFFFFu, t = row >> 6;
        u32 slot = atomicAdd(&cursor[t], 1u);
        ccol[slot] = (u16)col;
        crl[slot]  = (u8)(row & 63u);
    }
    __syncthreads();

    // ---- serial greedy: single wave, in-order DS, zero barriers ----
    if (tid < 64) {
        const int lane = tid;
        for (int t = 0; t < NT; ++t) {
            const u64 d = ldiag[t * 64 + lane];     // one conflict-free ds_read
            const u64 nz = __ballot(d != 0ull);     // poison lanes masked by valid below
            const int rem = N_BOXES - t * 64;
            const u64 valid = (rem >= 64) ? ~0ull : ((1ull << rem) - 1ull);
            u64 c = valid & ~removed[t];            // sees all earlier scatters
            u64 kw = 0;
            while (c) {
                u64 blockers = c & nz;
                if (!blockers) { kw |= c; break; }  // bulk-keep rest
                int g = (int)__builtin_ctzll(blockers);
                u64 below = c & ((1ull << g) - 1ull);
                kw |= below | (1ull << g);
                u64 df = rdlane64(d, g);            // bits > g only
                c &= ~(df | below | (1ull << g));
            }
            if (lane == 0) kwbuf[t] = kw;
            // edge-parallel scatter: lane = edge
            const u32 beg = tilestart[t], end = cursor[t];
            for (u32 b = beg + lane; b < end; b += 64) {
                if ((kw >> crl[b]) & 1ull) {
                    u32 col = ccol[b];
                    atomicOr(&removed[col >> 6], 1ull << (col & 63));
                }
            }
        }
    }
    __syncthreads();

    // ---- epilogue: masked scores through the sort permutation ----
    for (int p = tid; p < N_BOXES; p += 1024) {
        int orig = sidx[p];
        float s = scores[orig];
        bool k = (kwbuf[p >> 6] >> (p & 63)) & 1ull;
        out[orig] = (k && (s >= CONF_THR)) ? s : 0.0f;   // writes ALL outputs
    }
}

extern "C" void kernel_launch(void* const* d_in, const int* in_sizes, int n_in,
                              void* d_out, int out_size, void* d_ws, size_t ws_size,
                              hipStream_t stream) {
    const float* boxes  = (const float*)d_in[0];    // [6000,4]
    const float* scores = (const float*)d_in[1];    // [6000]
    float* out = (float*)d_out;                     // [6000]

    // workspace layout
    char* ws = (char*)d_ws;
    u32* edges  = (u32*)(ws);                       // 24576*4 = 98,304 B
    int* ecnt   = (int*)(ws + 98304);               // 16 B
    u64* diagw  = (u64*)(ws + 98320);               // 6016*8 = 48,128 B (8-aligned)
    int* sidx   = (int*)(ws + 146448);              // 24,000 B
    float4* sboxes = (float4*)(ws + 170448);        // 96,000 B (16-aligned)

    k_sort<<<dim3(NT), dim3(1024), 0, stream>>>(scores, (const float4*)boxes,
                                                sidx, sboxes, ecnt);
    k_mask<<<dim3(NT, NT), dim3(64), 0, stream>>>((const float4*)sboxes,
                                                  edges, ecnt, diagw);
    k_scan<<<dim3(1), dim3(1024), 0, stream>>>(edges, ecnt, diagw,
                                               sidx, scores, out);
}